// Round 1
// baseline (1815.924 us; speedup 1.0000x reference)
//
#include <hip/hip_runtime.h>

#define NB 32      // batch
#define NC 256     // planes
#define NO 128     // inplanes (output channels)
#define HH 28
#define HW 784     // 28*28
#define OH 56

// ---------------------------------------------------------------------------
// K1: per-(b,c) range = max - min over 28x28
// ---------------------------------------------------------------------------
__global__ void k_range(const float* __restrict__ x, float* __restrict__ rng) {
    int bc = blockIdx.x;               // b*NC + c
    int t = threadIdx.x;               // 256
    const float* p = x + (size_t)bc * HW;
    float mx = -1e30f, mn = 1e30f;
    for (int i = t; i < HW; i += 256) {
        float v = p[i];
        mx = fmaxf(mx, v);
        mn = fminf(mn, v);
    }
    __shared__ float smx[256], smn[256];
    smx[t] = mx; smn[t] = mn;
    __syncthreads();
    for (int s = 128; s > 0; s >>= 1) {
        if (t < s) {
            smx[t] = fmaxf(smx[t], smx[t + s]);
            smn[t] = fminf(smn[t], smn[t + s]);
        }
        __syncthreads();
    }
    if (t == 0) rng[bc] = smx[0] - smn[0];
}

// ---------------------------------------------------------------------------
// K2: stable argsort rank; keep top half in ascending-range order
// ---------------------------------------------------------------------------
__global__ void k_select(const float* __restrict__ rng, int* __restrict__ sel) {
    int b = blockIdx.x;
    int c = threadIdx.x;               // NC threads
    __shared__ float s[NC];
    s[c] = rng[b * NC + c];
    __syncthreads();
    float v = s[c];
    int rank = 0;
    for (int j = 0; j < NC; ++j) {
        float u = s[j];
        rank += (u < v) || (u == v && j < c);
    }
    if (rank >= NC / 2) sel[b * (NC / 2) + (rank - NC / 2)] = c;
}

// ---------------------------------------------------------------------------
// K3: conv_t(x + b1a, w_conv2, stride=1, pad=1); r1' = relu(t1 + b1b) + b2a
//   t1[b,o,y,x] = sum_{c,u,v} xpad[b,c,y+1-u,x+1-v] * w2[c,o,u,v]
// Block: (b, o-block of 8). 784 threads, 1 px each. LDS: 30x30 padded slice.
// ---------------------------------------------------------------------------
__global__ __launch_bounds__(784) void k_conv1(
    const float* __restrict__ x, const float* __restrict__ w2,
    const float* __restrict__ pb1a, const float* __restrict__ pb1b,
    const float* __restrict__ pb2a, float* __restrict__ r1)
{
    __shared__ float tile[30 * 30];
    int t = threadIdx.x;
    int b = blockIdx.x >> 5;
    int o0 = (blockIdx.x & 31) * 8;
    int py = t / 28, px = t % 28;
    float b1a = pb1a[0], b1b = pb1b[0], b2a = pb2a[0];

    // zero the 116 border cells once (interior rewritten every c)
    if (t < 30) tile[t] = 0.f;
    else if (t < 60) tile[29 * 30 + (t - 30)] = 0.f;
    else if (t < 88) tile[(t - 60 + 1) * 30] = 0.f;
    else if (t < 116) tile[(t - 88 + 1) * 30 + 29] = 0.f;

    float acc[8];
#pragma unroll
    for (int o = 0; o < 8; ++o) acc[o] = 0.f;

    const float* xb = x + (size_t)b * NC * HW;
    for (int c = 0; c < NC; ++c) {
        __syncthreads();
        tile[(py + 1) * 30 + (px + 1)] = xb[c * HW + t] + b1a;
        __syncthreads();
        float w[8][9];
#pragma unroll
        for (int o = 0; o < 8; ++o)
#pragma unroll
            for (int k = 0; k < 9; ++k)
                w[o][k] = w2[((size_t)(c * NC) + o0 + o) * 9 + k];
#pragma unroll
        for (int u = 0; u < 3; ++u)
#pragma unroll
            for (int v = 0; v < 3; ++v) {
                float xv = tile[(py + 2 - u) * 30 + (px + 2 - v)];
#pragma unroll
                for (int o = 0; o < 8; ++o)
                    acc[o] = fmaf(xv, w[o][u * 3 + v], acc[o]);
            }
    }
#pragma unroll
    for (int o = 0; o < 8; ++o)
        r1[((size_t)(b * NC + o0 + o)) * HW + t] = fmaxf(acc[o] + b1b, 0.f) + b2a;
}

// ---------------------------------------------------------------------------
// K4: fused conv_t(r1', w_conv1, stride=2, pad=1) * scale + b2b,
//     top-left pad, + upsample branch, relu, store.
// Each thread owns a 2x2 output quad (yo=2qy+ry, xo=2qx+rx) for 8 o-channels.
// Phase decomposition (exactly one tap set per parity):
//   acc00 += xd*w00 + xc*w02 + xb*w20 + xa*w22
//   acc01 += xd*w01 + xb*w21
//   acc10 += xd*w10 + xc*w12
//   acc11 += xd*w11
// where xd=r1[qy][qx], xc=r1[qy][qx-1], xb=r1[qy-1][qx], xa=r1[qy-1][qx-1].
// ---------------------------------------------------------------------------
__global__ __launch_bounds__(784) void k_conv2_fused(
    const float* __restrict__ r1, const float* __restrict__ x,
    const float* __restrict__ w1, const float* __restrict__ wup,
    const int* __restrict__ sel,
    const float* __restrict__ pb1a, const float* __restrict__ pscale,
    const float* __restrict__ pb2b, float* __restrict__ out)
{
    __shared__ float tile[HW];
    int t = threadIdx.x;
    int b = blockIdx.x >> 4;
    int o0 = (blockIdx.x & 15) * 8;
    int qy = t / 28, qx = t % 28;
    float b1a = pb1a[0], scale = pscale[0], b2b = pb2b[0];

    float acc[32];
#pragma unroll
    for (int i = 0; i < 32; ++i) acc[i] = 0.f;

    const float* r1b = r1 + (size_t)b * NC * HW;
    for (int c = 0; c < NC; ++c) {
        __syncthreads();
        tile[t] = r1b[c * HW + t];
        __syncthreads();
        float xd = tile[qy * 28 + qx];
        float xc = (qx > 0) ? tile[qy * 28 + qx - 1] : 0.f;
        float xb = (qy > 0) ? tile[(qy - 1) * 28 + qx] : 0.f;
        float xa = (qy > 0 && qx > 0) ? tile[(qy - 1) * 28 + qx - 1] : 0.f;
#pragma unroll
        for (int o = 0; o < 8; ++o) {
            const float* wp = w1 + ((size_t)c * NO + o0 + o) * 9;
            float w0 = wp[0], w1_ = wp[1], w2_ = wp[2];
            float w3 = wp[3], w4 = wp[4], w5 = wp[5];
            float w6 = wp[6], w7 = wp[7], w8 = wp[8];
            acc[o * 4 + 0] = fmaf(xd, w0, fmaf(xc, w2_, fmaf(xb, w6, fmaf(xa, w8, acc[o * 4 + 0]))));
            acc[o * 4 + 1] = fmaf(xd, w1_, fmaf(xb, w7, acc[o * 4 + 1]));
            acc[o * 4 + 2] = fmaf(xd, w3, fmaf(xc, w5, acc[o * 4 + 2]));
            acc[o * 4 + 3] = fmaf(xd, w4, acc[o * 4 + 3]);
        }
    }

    // main-branch transform: scale+bias where valid, 0 on pad row/col (yo==0 or xo==0)
    bool zr = (qy == 0), zc = (qx == 0);
#pragma unroll
    for (int o = 0; o < 8; ++o) {
        acc[o * 4 + 0] = (zr || zc) ? 0.f : fmaf(acc[o * 4 + 0], scale, b2b);
        acc[o * 4 + 1] = zr ? 0.f : fmaf(acc[o * 4 + 1], scale, b2b);
        acc[o * 4 + 2] = zc ? 0.f : fmaf(acc[o * 4 + 2], scale, b2b);
        acc[o * 4 + 3] = fmaf(acc[o * 4 + 3], scale, b2b);
    }

    // upsample branch: identity[yo,xo] = sum_k (x[b,sel[k],qy,qx]+b1a) * wup[k,o,ry,rx]
    const float* xbase = x + (size_t)b * NC * HW;
    const int* selb = sel + b * NO;
    for (int k = 0; k < NO; ++k) {
        int ch = selb[k];
        float xs = xbase[ch * HW + t] + b1a;
        const float* wu = wup + ((size_t)k * NO + o0) * 4;
#pragma unroll
        for (int o = 0; o < 8; ++o) {
            acc[o * 4 + 0] = fmaf(xs, wu[o * 4 + 0], acc[o * 4 + 0]);
            acc[o * 4 + 1] = fmaf(xs, wu[o * 4 + 1], acc[o * 4 + 1]);
            acc[o * 4 + 2] = fmaf(xs, wu[o * 4 + 2], acc[o * 4 + 2]);
            acc[o * 4 + 3] = fmaf(xs, wu[o * 4 + 3], acc[o * 4 + 3]);
        }
    }

    // relu + store (float2: xo, xo+1 contiguous, 8B aligned)
    int yo = 2 * qy, xo = 2 * qx;
#pragma unroll
    for (int o = 0; o < 8; ++o) {
        size_t base = ((size_t)(b * NO + o0 + o) * OH + yo) * OH + xo;
        float2 v0 = { fmaxf(acc[o * 4 + 0], 0.f), fmaxf(acc[o * 4 + 1], 0.f) };
        float2 v1 = { fmaxf(acc[o * 4 + 2], 0.f), fmaxf(acc[o * 4 + 3], 0.f) };
        *reinterpret_cast<float2*>(&out[base]) = v0;
        *reinterpret_cast<float2*>(&out[base + OH]) = v1;
    }
}

// ---------------------------------------------------------------------------
extern "C" void kernel_launch(void* const* d_in, const int* in_sizes, int n_in,
                              void* d_out, int out_size, void* d_ws, size_t ws_size,
                              hipStream_t stream)
{
    const float* x     = (const float*)d_in[0];
    const float* w2    = (const float*)d_in[1];
    const float* w1    = (const float*)d_in[2];
    const float* wup   = (const float*)d_in[3];
    const float* b1a   = (const float*)d_in[4];
    const float* b1b   = (const float*)d_in[5];
    const float* b2a   = (const float*)d_in[6];
    const float* b2b   = (const float*)d_in[7];
    const float* scale = (const float*)d_in[8];

    float* r1  = (float*)d_ws;                       // 32*256*784 floats = 25.7 MB
    float* rng = r1 + (size_t)NB * NC * HW;          // 8192 floats
    int*   sel = (int*)(rng + NB * NC);              // 4096 ints
    float* out = (float*)d_out;

    hipLaunchKernelGGL(k_range, dim3(NB * NC), dim3(256), 0, stream, x, rng);
    hipLaunchKernelGGL(k_select, dim3(NB), dim3(NC), 0, stream, rng, sel);
    hipLaunchKernelGGL(k_conv1, dim3(NB * 32), dim3(784), 0, stream,
                       x, w2, b1a, b1b, b2a, r1);
    hipLaunchKernelGGL(k_conv2_fused, dim3(NB * 16), dim3(784), 0, stream,
                       r1, x, w1, wup, sel, b1a, scale, b2b, out);
}

// Round 2
// 808.504 us; speedup vs baseline: 2.2460x; 2.2460x over previous
//
#include <hip/hip_runtime.h>

#define NB 32      // batch
#define NC 256     // planes
#define NO 128     // inplanes (output channels)
#define HH 28
#define HW 784     // 28*28
#define OH 56

typedef unsigned short u16;
typedef __attribute__((ext_vector_type(8))) short bf16x8;
typedef __attribute__((ext_vector_type(4))) float f32x4;
typedef __attribute__((ext_vector_type(4))) unsigned short u16x4;
typedef __attribute__((ext_vector_type(8))) unsigned short u16x8;

__device__ __forceinline__ u16 f2bf(float f) {
    unsigned u = __float_as_uint(f);
    unsigned r = (u + 0x7fffu + ((u >> 16) & 1u)) >> 16;
    return (u16)r;
}
__device__ __forceinline__ float bf2f(u16 v) {
    return __uint_as_float(((unsigned)v) << 16);
}

// ---------------------------------------------------------------------------
// Pack weights: wT2[tap=dy*3+dx][cb=c/8][o][ci=c%8] = w2[c][o][2-dy][2-dx]
// ---------------------------------------------------------------------------
__global__ void k_pack_w(const float* __restrict__ w2, u16* __restrict__ wT2) {
    int g = blockIdx.x * 256 + threadIdx.x;          // 9*32*256 = 73728 groups
    int o = g & 255;
    int cb = (g >> 8) & 31;
    int tap = g >> 13;
    int u = 2 - tap / 3, v = 2 - tap % 3;
    u16x8 out;
#pragma unroll
    for (int ci = 0; ci < 8; ++ci) {
        int c = cb * 8 + ci;
        out[ci] = f2bf(w2[((c * NC + o) * 3 + u) * 3 + v]);
    }
    *(u16x8*)(wT2 + (size_t)g * 8) = out;
}

// ---------------------------------------------------------------------------
// Pack x: xT2[b][ry 0..29][cb 0..31][cx 0..31][ci 0..7] bf16
//   value = (y,x in-bounds) ? x[b][c][y][x] + b1a : 0   (y=ry-1, x=cx-1)
// ---------------------------------------------------------------------------
__global__ void k_pack_x(const float* __restrict__ x, const float* __restrict__ pb1a,
                         u16* __restrict__ xT2) {
    int g = blockIdx.x * 256 + threadIdx.x;          // 32*30*32*32 = 983040 groups
    float b1a = pb1a[0];
    int cx = g & 31;
    int cb = (g >> 5) & 31;
    int bry = g >> 10;                               // b*30 + ry
    int b = bry / 30;
    int ry = bry - b * 30;
    int y = ry - 1, xx = cx - 1;
    bool valid = (y >= 0 && y < HH && xx >= 0 && xx < HH);
    const float* xb = x + (size_t)b * NC * HW + (valid ? y * 28 + xx : 0);
    u16x8 out;
#pragma unroll
    for (int ci = 0; ci < 8; ++ci) {
        float f = valid ? xb[(cb * 8 + ci) * HW] + b1a : 0.f;
        out[ci] = f2bf(f);
    }
    *(u16x8*)(xT2 + (size_t)g * 8) = out;
}

// ---------------------------------------------------------------------------
// K1: per-(b,c) range = max - min over 28x28
// ---------------------------------------------------------------------------
__global__ void k_range(const float* __restrict__ x, float* __restrict__ rng) {
    int bc = blockIdx.x;
    int t = threadIdx.x;
    const float* p = x + (size_t)bc * HW;
    float mx = -1e30f, mn = 1e30f;
    for (int i = t; i < HW; i += 256) {
        float v = p[i];
        mx = fmaxf(mx, v);
        mn = fminf(mn, v);
    }
    __shared__ float smx[256], smn[256];
    smx[t] = mx; smn[t] = mn;
    __syncthreads();
    for (int s = 128; s > 0; s >>= 1) {
        if (t < s) {
            smx[t] = fmaxf(smx[t], smx[t + s]);
            smn[t] = fminf(smn[t], smn[t + s]);
        }
        __syncthreads();
    }
    if (t == 0) rng[bc] = smx[0] - smn[0];
}

// ---------------------------------------------------------------------------
// K2: stable argsort rank; keep top half in ascending-range order
// ---------------------------------------------------------------------------
__global__ void k_select(const float* __restrict__ rng, int* __restrict__ sel) {
    int b = blockIdx.x;
    int c = threadIdx.x;
    __shared__ float s[NC];
    s[c] = rng[b * NC + c];
    __syncthreads();
    float v = s[c];
    int rank = 0;
    for (int j = 0; j < NC; ++j) {
        float u = s[j];
        rank += (u < v) || (u == v && j < c);
    }
    if (rank >= NC / 2) sel[b * (NC / 2) + (rank - NC / 2)] = c;
}

// ---------------------------------------------------------------------------
// conv1 via MFMA: r1'[b][o][y][x] = relu(conv(xpad, w2)[o,y,x] + b1b) + b2a
// GEMM view: M=pixels (padded 32-wide rows), N=256 o, K=9 taps x 256 c.
// Block: 4 output rows x 32 cols x 256 o. 8 waves = 2(pix) x 4(o).
// Wave: 4 pixel-tiles (2 rows x 2 col-halves) x 4 o-tiles, acc 4x4x4 f32.
// Fragments read directly from global (L1/L2-hot packed layouts, no LDS).
// ---------------------------------------------------------------------------
__global__ __launch_bounds__(512, 4) void k_conv1_mfma(
    const u16* __restrict__ xT2, const u16* __restrict__ wT2,
    const float* __restrict__ pb1b, const float* __restrict__ pb2a,
    u16* __restrict__ r1bf)
{
    int tid = threadIdx.x;
    int wave = tid >> 6, lane = tid & 63;
    int wpi = wave >> 2;              // pixel-row group 0..1
    int wo = wave & 3;                // o-group 0..3 (64 o each)
    int l15 = lane & 15, lg = lane >> 4;

    int b = blockIdx.x / 7;
    int rg = blockIdx.x - b * 7;
    int y0 = rg * 4;

    float b1b = pb1b[0], b2a = pb2a[0];

    // per-lane byte offsets at (dy=0,dx=0,c0=0)
    int aOff[4], bOff[4];
#pragma unroll
    for (int pt = 0; pt < 4; ++pt) {
        int ry = y0 + 2 * wpi + (pt >> 1);
        int cx = (pt & 1) * 16 + l15;
        aOff[pt] = (((b * 30 + ry) * 32 + lg) * 32 + cx) * 16;
    }
#pragma unroll
    for (int ot = 0; ot < 4; ++ot)
        bOff[ot] = (lg * 256 + (wo * 64 + ot * 16 + l15)) * 16;

    f32x4 acc[4][4] = {};

    const char* xp = (const char*)xT2;
    const char* wq = (const char*)wT2;

    for (int c0 = 0; c0 < 256; c0 += 32) {
#pragma unroll
        for (int tap = 0; tap < 9; ++tap) {
            const int dy = tap / 3, dx = tap % 3;
            int koffA = c0 * 64 + dy * 16384 + dx * 16;
            int koffB = tap * 131072 + c0 * 512;
            bf16x8 a[4], w[4];
#pragma unroll
            for (int pt = 0; pt < 4; ++pt)
                a[pt] = *(const bf16x8*)(xp + (aOff[pt] + koffA));
#pragma unroll
            for (int ot = 0; ot < 4; ++ot)
                w[ot] = *(const bf16x8*)(wq + (bOff[ot] + koffB));
#pragma unroll
            for (int pt = 0; pt < 4; ++pt)
#pragma unroll
                for (int ot = 0; ot < 4; ++ot)
                    acc[pt][ot] = __builtin_amdgcn_mfma_f32_16x16x32_bf16(
                        a[pt], w[ot], acc[pt][ot], 0, 0, 0);
        }
    }

    // epilogue: relu(acc + b1b) + b2a -> bf16 r1[b][o][y*28+x], 4 consecutive x per lane
#pragma unroll
    for (int pt = 0; pt < 4; ++pt) {
        int y = y0 + 2 * wpi + (pt >> 1);
        int x = (pt & 1) * 16 + lg * 4;
        if (x >= 28) continue;
#pragma unroll
        for (int ot = 0; ot < 4; ++ot) {
            int o = wo * 64 + ot * 16 + l15;
            u16x4 v;
#pragma unroll
            for (int r = 0; r < 4; ++r) {
                float f = fmaxf(acc[pt][ot][r] + b1b, 0.f) + b2a;
                v[r] = f2bf(f);
            }
            *(u16x4*)(r1bf + ((b * NC + o) * HW + y * 28 + x)) = v;
        }
    }
}

// ---------------------------------------------------------------------------
// K4: fused conv_t(r1', w_conv1, stride=2, pad=1) * scale + b2b,
//     top-left pad, + upsample branch, relu, store.  (r1' now bf16)
// ---------------------------------------------------------------------------
__global__ __launch_bounds__(784) void k_conv2_fused(
    const u16* __restrict__ r1, const float* __restrict__ x,
    const float* __restrict__ w1, const float* __restrict__ wup,
    const int* __restrict__ sel,
    const float* __restrict__ pb1a, const float* __restrict__ pscale,
    const float* __restrict__ pb2b, float* __restrict__ out)
{
    __shared__ float tile[HW];
    int t = threadIdx.x;
    int b = blockIdx.x >> 4;
    int o0 = (blockIdx.x & 15) * 8;
    int qy = t / 28, qx = t % 28;
    float b1a = pb1a[0], scale = pscale[0], b2b = pb2b[0];

    float acc[32];
#pragma unroll
    for (int i = 0; i < 32; ++i) acc[i] = 0.f;

    const u16* r1b = r1 + (size_t)b * NC * HW;
    for (int c = 0; c < NC; ++c) {
        __syncthreads();
        tile[t] = bf2f(r1b[c * HW + t]);
        __syncthreads();
        float xd = tile[qy * 28 + qx];
        float xc = (qx > 0) ? tile[qy * 28 + qx - 1] : 0.f;
        float xb = (qy > 0) ? tile[(qy - 1) * 28 + qx] : 0.f;
        float xa = (qy > 0 && qx > 0) ? tile[(qy - 1) * 28 + qx - 1] : 0.f;
#pragma unroll
        for (int o = 0; o < 8; ++o) {
            const float* wp = w1 + ((size_t)c * NO + o0 + o) * 9;
            float w0 = wp[0], w1_ = wp[1], w2_ = wp[2];
            float w3 = wp[3], w4 = wp[4], w5 = wp[5];
            float w6 = wp[6], w7 = wp[7], w8 = wp[8];
            acc[o * 4 + 0] = fmaf(xd, w0, fmaf(xc, w2_, fmaf(xb, w6, fmaf(xa, w8, acc[o * 4 + 0]))));
            acc[o * 4 + 1] = fmaf(xd, w1_, fmaf(xb, w7, acc[o * 4 + 1]));
            acc[o * 4 + 2] = fmaf(xd, w3, fmaf(xc, w5, acc[o * 4 + 2]));
            acc[o * 4 + 3] = fmaf(xd, w4, acc[o * 4 + 3]);
        }
    }

    bool zr = (qy == 0), zc = (qx == 0);
#pragma unroll
    for (int o = 0; o < 8; ++o) {
        acc[o * 4 + 0] = (zr || zc) ? 0.f : fmaf(acc[o * 4 + 0], scale, b2b);
        acc[o * 4 + 1] = zr ? 0.f : fmaf(acc[o * 4 + 1], scale, b2b);
        acc[o * 4 + 2] = zc ? 0.f : fmaf(acc[o * 4 + 2], scale, b2b);
        acc[o * 4 + 3] = fmaf(acc[o * 4 + 3], scale, b2b);
    }

    const float* xbase = x + (size_t)b * NC * HW;
    const int* selb = sel + b * NO;
    for (int k = 0; k < NO; ++k) {
        int ch = selb[k];
        float xs = xbase[ch * HW + t] + b1a;
        const float* wu = wup + ((size_t)k * NO + o0) * 4;
#pragma unroll
        for (int o = 0; o < 8; ++o) {
            acc[o * 4 + 0] = fmaf(xs, wu[o * 4 + 0], acc[o * 4 + 0]);
            acc[o * 4 + 1] = fmaf(xs, wu[o * 4 + 1], acc[o * 4 + 1]);
            acc[o * 4 + 2] = fmaf(xs, wu[o * 4 + 2], acc[o * 4 + 2]);
            acc[o * 4 + 3] = fmaf(xs, wu[o * 4 + 3], acc[o * 4 + 3]);
        }
    }

    int yo = 2 * qy, xo = 2 * qx;
#pragma unroll
    for (int o = 0; o < 8; ++o) {
        size_t base = ((size_t)(b * NO + o0 + o) * OH + yo) * OH + xo;
        float2 v0 = { fmaxf(acc[o * 4 + 0], 0.f), fmaxf(acc[o * 4 + 1], 0.f) };
        float2 v1 = { fmaxf(acc[o * 4 + 2], 0.f), fmaxf(acc[o * 4 + 3], 0.f) };
        *reinterpret_cast<float2*>(&out[base]) = v0;
        *reinterpret_cast<float2*>(&out[base + OH]) = v1;
    }
}

// ---------------------------------------------------------------------------
extern "C" void kernel_launch(void* const* d_in, const int* in_sizes, int n_in,
                              void* d_out, int out_size, void* d_ws, size_t ws_size,
                              hipStream_t stream)
{
    const float* x     = (const float*)d_in[0];
    const float* w2    = (const float*)d_in[1];
    const float* w1    = (const float*)d_in[2];
    const float* wup   = (const float*)d_in[3];
    const float* b1a   = (const float*)d_in[4];
    const float* b1b   = (const float*)d_in[5];
    const float* b2a   = (const float*)d_in[6];
    const float* b2b   = (const float*)d_in[7];
    const float* scale = (const float*)d_in[8];

    u16* xT2  = (u16*)d_ws;                              // 32*30*32*32*8 u16 = 15.7 MB
    u16* r1bf = xT2 + (size_t)32 * 30 * 32 * 32 * 8;     // 32*256*784 u16 = 12.8 MB
    float* rng = (float*)(r1bf + (size_t)NB * NC * HW);  // 8192 f32
    int* sel   = (int*)(rng + NB * NC);                  // 4096 i32
    u16* wT2   = (u16*)(sel + NB * (NC / 2));            // 9*32*256*8 u16 = 1.18 MB
    float* out = (float*)d_out;

    hipLaunchKernelGGL(k_pack_w, dim3(288), dim3(256), 0, stream, w2, wT2);
    hipLaunchKernelGGL(k_pack_x, dim3(3840), dim3(256), 0, stream, x, b1a, xT2);
    hipLaunchKernelGGL(k_range, dim3(NB * NC), dim3(256), 0, stream, x, rng);
    hipLaunchKernelGGL(k_select, dim3(NB), dim3(NC), 0, stream, rng, sel);
    hipLaunchKernelGGL(k_conv1_mfma, dim3(NB * 7), dim3(512), 0, stream,
                       xT2, wT2, b1b, b2a, r1bf);
    hipLaunchKernelGGL(k_conv2_fused, dim3(NB * 16), dim3(784), 0, stream,
                       r1bf, x, w1, wup, sel, b1a, scale, b2b, out);
}

// Round 3
// 150.758 us; speedup vs baseline: 12.0453x; 5.3629x over previous
//
#include <hip/hip_runtime.h>

#define NB 32      // batch
#define NC 256     // planes
#define NO 128     // inplanes (output channels)
#define HH 28
#define HW 784     // 28*28
#define OH 56

typedef unsigned short u16;
typedef __attribute__((ext_vector_type(8))) short bf16x8;
typedef __attribute__((ext_vector_type(4))) float f32x4;
typedef __attribute__((ext_vector_type(8))) unsigned short u16x8;

#define MFMA(A,B,C) __builtin_amdgcn_mfma_f32_16x16x32_bf16(A,B,C,0,0,0)

__device__ __forceinline__ u16 f2bf(float f) {
    unsigned u = __float_as_uint(f);
    unsigned r = (u + 0x7fffu + ((u >> 16) & 1u)) >> 16;
    return (u16)r;
}

// ---------------------------------------------------------------------------
// zero-fill (16B granules)
// ---------------------------------------------------------------------------
__global__ void k_zero(uint4* __restrict__ p, int n) {
    int g = blockIdx.x * 256 + threadIdx.x;
    if (g < n) p[g] = make_uint4(0, 0, 0, 0);
}

// ---------------------------------------------------------------------------
// Pack conv1 weights: wT2[tap=dy*3+dx][cb][o][ci] = w2[c][o][2-dy][2-dx]
// ---------------------------------------------------------------------------
__global__ void k_pack_w(const float* __restrict__ w2, u16* __restrict__ wT2) {
    int g = blockIdx.x * 256 + threadIdx.x;          // 9*32*256
    int o = g & 255;
    int cb = (g >> 8) & 31;
    int tap = g >> 13;
    int u = 2 - tap / 3, v = 2 - tap % 3;
    u16x8 out;
#pragma unroll
    for (int ci = 0; ci < 8; ++ci) {
        int c = cb * 8 + ci;
        out[ci] = f2bf(w2[((c * NC + o) * 3 + u) * 3 + v]);
    }
    *(u16x8*)(wT2 + (size_t)g * 8) = out;
}

// ---------------------------------------------------------------------------
// Pack conv2 weights by parity-slot: slots s=0..8 -> taps {0,2,6,8,1,7,3,5,4}
// wc2T[s][cb][o][ci] = w1[c][o][tap_s]
// ---------------------------------------------------------------------------
__global__ void k_pack_wc2(const float* __restrict__ w1, u16* __restrict__ wc2T) {
    const int taps[9] = {0, 2, 6, 8, 1, 7, 3, 5, 4};
    int g = blockIdx.x * 256 + threadIdx.x;          // 9*32*128 = 36864
    int o = g & 127;
    int cb = (g >> 7) & 31;
    int s = g >> 12;
    int tap = taps[s];
    u16x8 out;
#pragma unroll
    for (int ci = 0; ci < 8; ++ci) {
        int c = cb * 8 + ci;
        out[ci] = f2bf(w1[(c * NO + o) * 9 + tap]);
    }
    *(u16x8*)(wc2T + (size_t)g * 8) = out;
}

// ---------------------------------------------------------------------------
// Pack upsample weights: wupT[p][kb][o][ki] = wup[k][o][p]  (p = ry*2+rx)
// ---------------------------------------------------------------------------
__global__ void k_pack_wup(const float* __restrict__ wup, u16* __restrict__ wupT) {
    int g = blockIdx.x * 256 + threadIdx.x;          // 4*16*128 = 8192
    int o = g & 127;
    int kb = (g >> 7) & 15;
    int p = g >> 11;
    u16x8 out;
#pragma unroll
    for (int ki = 0; ki < 8; ++ki) {
        int k = kb * 8 + ki;
        out[ki] = f2bf(wup[(k * NO + o) * 4 + p]);
    }
    *(u16x8*)(wupT + (size_t)g * 8) = out;
}

// ---------------------------------------------------------------------------
// Pack x: xT2[b][ry 0..29][cb][cx 0..31][ci], value = x[b][c][ry-1][cx-1]+b1a or 0
// ---------------------------------------------------------------------------
__global__ void k_pack_x(const float* __restrict__ x, const float* __restrict__ pb1a,
                         u16* __restrict__ xT2) {
    int g = blockIdx.x * 256 + threadIdx.x;          // 32*30*32*32 = 983040
    float b1a = pb1a[0];
    int cx = g & 31;
    int cb = (g >> 5) & 31;
    int bry = g >> 10;
    int b = bry / 30;
    int ry = bry - b * 30;
    int y = ry - 1, xx = cx - 1;
    bool valid = (y >= 0 && y < HH && xx >= 0 && xx < HH);
    const float* xb = x + (size_t)b * NC * HW + (valid ? y * 28 + xx : 0);
    u16x8 out;
#pragma unroll
    for (int ci = 0; ci < 8; ++ci) {
        float f = valid ? xb[(cb * 8 + ci) * HW] + b1a : 0.f;
        out[ci] = f2bf(f);
    }
    *(u16x8*)(xT2 + (size_t)g * 8) = out;
}

// ---------------------------------------------------------------------------
// Gather-pack selected channels: xupT[b][qy][kb][cx][ki] = x[b][sel[k]][qy][cx]+b1a
// (cx>=28 zero-padded)
// ---------------------------------------------------------------------------
__global__ void k_pack_xup(const float* __restrict__ x, const int* __restrict__ sel,
                           const float* __restrict__ pb1a, u16* __restrict__ xupT) {
    int g = blockIdx.x * 256 + threadIdx.x;          // 32*28*16*32 = 458752
    float b1a = pb1a[0];
    int cx = g & 31;
    int kb = (g >> 5) & 15;
    int qyb = g >> 9;                                // b*28 + qy
    int b = qyb / 28;
    int qy = qyb - b * 28;
    bool valid = cx < 28;
    const int* selb = sel + b * NO;
    const float* xb = x + (size_t)b * NC * HW + qy * 28 + (valid ? cx : 0);
    u16x8 out;
#pragma unroll
    for (int ki = 0; ki < 8; ++ki) {
        int ch = selb[kb * 8 + ki];
        float f = valid ? xb[ch * HW] + b1a : 0.f;
        out[ki] = f2bf(f);
    }
    *(u16x8*)(xupT + (size_t)g * 8) = out;
}

// ---------------------------------------------------------------------------
// K1: per-(b,c) range
// ---------------------------------------------------------------------------
__global__ void k_range(const float* __restrict__ x, float* __restrict__ rng) {
    int bc = blockIdx.x;
    int t = threadIdx.x;
    const float* p = x + (size_t)bc * HW;
    float mx = -1e30f, mn = 1e30f;
    for (int i = t; i < HW; i += 256) {
        float v = p[i];
        mx = fmaxf(mx, v);
        mn = fminf(mn, v);
    }
    __shared__ float smx[256], smn[256];
    smx[t] = mx; smn[t] = mn;
    __syncthreads();
    for (int s = 128; s > 0; s >>= 1) {
        if (t < s) {
            smx[t] = fmaxf(smx[t], smx[t + s]);
            smn[t] = fminf(smn[t], smn[t + s]);
        }
        __syncthreads();
    }
    if (t == 0) rng[bc] = smx[0] - smn[0];
}

// ---------------------------------------------------------------------------
// K2: stable argsort rank; keep top half ascending
// ---------------------------------------------------------------------------
__global__ void k_select(const float* __restrict__ rng, int* __restrict__ sel) {
    int b = blockIdx.x;
    int c = threadIdx.x;
    __shared__ float s[NC];
    s[c] = rng[b * NC + c];
    __syncthreads();
    float v = s[c];
    int rank = 0;
    for (int j = 0; j < NC; ++j) {
        float u = s[j];
        rank += (u < v) || (u == v && j < c);
    }
    if (rank >= NC / 2) sel[b * (NC / 2) + (rank - NC / 2)] = c;
}

// ---------------------------------------------------------------------------
// conv1 via MFMA -> writes r1' into padded MFMA layout r1T[b][ry][cb][cx][ci]
// ---------------------------------------------------------------------------
__global__ __launch_bounds__(512, 4) void k_conv1_mfma(
    const u16* __restrict__ xT2, const u16* __restrict__ wT2,
    const float* __restrict__ pb1b, const float* __restrict__ pb2a,
    u16* __restrict__ r1T)
{
    int tid = threadIdx.x;
    int wave = tid >> 6, lane = tid & 63;
    int wpi = wave >> 2;
    int wo = wave & 3;
    int l15 = lane & 15, lg = lane >> 4;

    int b = blockIdx.x / 7;
    int rg = blockIdx.x - b * 7;
    int y0 = rg * 4;

    float b1b = pb1b[0], b2a = pb2a[0];

    int aOff[4], bOff[4];
#pragma unroll
    for (int pt = 0; pt < 4; ++pt) {
        int ry = y0 + 2 * wpi + (pt >> 1);
        int cx = (pt & 1) * 16 + l15;
        aOff[pt] = (((b * 30 + ry) * 32 + lg) * 32 + cx) * 16;
    }
#pragma unroll
    for (int ot = 0; ot < 4; ++ot)
        bOff[ot] = (lg * 256 + (wo * 64 + ot * 16 + l15)) * 16;

    f32x4 acc[4][4] = {};
    const char* xp = (const char*)xT2;
    const char* wq = (const char*)wT2;

    for (int c0 = 0; c0 < 256; c0 += 32) {
#pragma unroll
        for (int tap = 0; tap < 9; ++tap) {
            const int dy = tap / 3, dx = tap % 3;
            int koffA = c0 * 64 + dy * 16384 + dx * 16;
            int koffB = tap * 131072 + c0 * 512;
            bf16x8 a[4], w[4];
#pragma unroll
            for (int pt = 0; pt < 4; ++pt)
                a[pt] = *(const bf16x8*)(xp + (aOff[pt] + koffA));
#pragma unroll
            for (int ot = 0; ot < 4; ++ot)
                w[ot] = *(const bf16x8*)(wq + (bOff[ot] + koffB));
#pragma unroll
            for (int pt = 0; pt < 4; ++pt)
#pragma unroll
                for (int ot = 0; ot < 4; ++ot)
                    acc[pt][ot] = MFMA(a[pt], w[ot], acc[pt][ot]);
        }
    }

    // epilogue: relu(acc+b1b)+b2a -> r1T[b][y+1][o/8][x+1][o%8]
#pragma unroll
    for (int pt = 0; pt < 4; ++pt) {
        int y = y0 + 2 * wpi + (pt >> 1);
        int x0 = (pt & 1) * 16 + lg * 4;
        if (x0 >= 28) continue;
#pragma unroll
        for (int ot = 0; ot < 4; ++ot) {
            int o = wo * 64 + ot * 16 + l15;
            size_t base = ((((size_t)b * 30 + y + 1) * 32 + (o >> 3)) * 32 + (x0 + 1)) * 8 + (o & 7);
#pragma unroll
            for (int r = 0; r < 4; ++r) {
                float f = fmaxf(acc[pt][ot][r] + b1b, 0.f) + b2a;
                r1T[base + (size_t)r * 8] = f2bf(f);
            }
        }
    }
}

// ---------------------------------------------------------------------------
// conv2 + upsample via MFMA.
// Per block: batch b, 4 qy rows, 32 qx, 128 o, 4 parities.
// 8 waves = 2(qy-pair) x 4(o-group of 32). Wave: 4 pixel-tiles x 2 o-tiles.
// A variants xd/xc/xb/xa are address shifts into padded r1T.
// Order: conv K-loop -> (pad-zero | *scale+b2b) -> upsample K-loop -> relu.
// ---------------------------------------------------------------------------
__global__ __launch_bounds__(512, 2) void k_conv2_mfma(
    const u16* __restrict__ r1T, const u16* __restrict__ xupT,
    const u16* __restrict__ wc2T, const u16* __restrict__ wupT,
    const float* __restrict__ pscale, const float* __restrict__ pb2b,
    float* __restrict__ out)
{
    int tid = threadIdx.x;
    int wave = tid >> 6, lane = tid & 63;
    int wpi = wave >> 2;
    int wo = wave & 3;
    int l15 = lane & 15, lg = lane >> 4;

    int b = blockIdx.x / 7;
    int rg = blockIdx.x - b * 7;
    int y0 = rg * 4;

    float scale = pscale[0], b2b = pb2b[0];

    f32x4 acc[4][4][2] = {};   // [parity][pixel-tile][o-tile]

    const char* rp = (const char*)r1T;
    const char* wp = (const char*)wc2T;

    int aBase[4];
#pragma unroll
    for (int pt = 0; pt < 4; ++pt) {
        int qy = y0 + 2 * wpi + (pt >> 1);
        int qt = pt & 1;
        aBase[pt] = (((b * 30 + qy + 1) * 32 + lg) * 32 + (qt * 16 + l15 + 1)) * 16;
    }
    int bBase = (lg * 128 + wo * 32 + l15) * 16;

    for (int c0 = 0; c0 < 256; c0 += 32) {
        bf16x8 w[9][2];
#pragma unroll
        for (int s = 0; s < 9; ++s)
#pragma unroll
            for (int ot = 0; ot < 2; ++ot)
                w[s][ot] = *(const bf16x8*)(wp + (bBase + s * 65536 + c0 * 256 + ot * 256));
#pragma unroll
        for (int pt = 0; pt < 4; ++pt) {
            const char* ap = rp + (aBase[pt] + c0 * 64);
            bf16x8 aD = *(const bf16x8*)(ap);
            bf16x8 aC = *(const bf16x8*)(ap - 16);
            bf16x8 aB = *(const bf16x8*)(ap - 16384);
            bf16x8 aA = *(const bf16x8*)(ap - 16400);
#pragma unroll
            for (int ot = 0; ot < 2; ++ot) {
                acc[0][pt][ot] = MFMA(aD, w[0][ot], acc[0][pt][ot]);
                acc[0][pt][ot] = MFMA(aC, w[1][ot], acc[0][pt][ot]);
                acc[0][pt][ot] = MFMA(aB, w[2][ot], acc[0][pt][ot]);
                acc[0][pt][ot] = MFMA(aA, w[3][ot], acc[0][pt][ot]);
                acc[1][pt][ot] = MFMA(aD, w[4][ot], acc[1][pt][ot]);
                acc[1][pt][ot] = MFMA(aB, w[5][ot], acc[1][pt][ot]);
                acc[2][pt][ot] = MFMA(aD, w[6][ot], acc[2][pt][ot]);
                acc[2][pt][ot] = MFMA(aC, w[7][ot], acc[2][pt][ot]);
                acc[3][pt][ot] = MFMA(aD, w[8][ot], acc[3][pt][ot]);
            }
        }
    }

    // mid-transform: pad-zero / scale+b2b (before upsample accumulation)
#pragma unroll
    for (int pt = 0; pt < 4; ++pt) {
        int qy = y0 + 2 * wpi + (pt >> 1);
        int qt = pt & 1;
        int qx0 = qt * 16 + lg * 4;
        bool zr = (qy == 0);
#pragma unroll
        for (int ot = 0; ot < 2; ++ot)
#pragma unroll
            for (int r = 0; r < 4; ++r) {
                bool zc = (qx0 + r == 0);
                float a0 = acc[0][pt][ot][r], a1 = acc[1][pt][ot][r];
                float a2 = acc[2][pt][ot][r], a3 = acc[3][pt][ot][r];
                acc[0][pt][ot][r] = (zr || zc) ? 0.f : fmaf(a0, scale, b2b);
                acc[1][pt][ot][r] = zr ? 0.f : fmaf(a1, scale, b2b);
                acc[2][pt][ot][r] = zc ? 0.f : fmaf(a2, scale, b2b);
                acc[3][pt][ot][r] = fmaf(a3, scale, b2b);
            }
    }

    // upsample accumulation
    const char* up = (const char*)xupT;
    const char* wu = (const char*)wupT;
    int uBaseA[4];
#pragma unroll
    for (int pt = 0; pt < 4; ++pt) {
        int qy = y0 + 2 * wpi + (pt >> 1);
        int qt = pt & 1;
        uBaseA[pt] = (((b * 28 + qy) * 16 + lg) * 32 + (qt * 16 + l15)) * 16;
    }
    for (int k0 = 0; k0 < 128; k0 += 32) {
        bf16x8 wb[4][2];
#pragma unroll
        for (int p = 0; p < 4; ++p)
#pragma unroll
            for (int ot = 0; ot < 2; ++ot)
                wb[p][ot] = *(const bf16x8*)(wu + (bBase + p * 32768 + k0 * 256 + ot * 256));
#pragma unroll
        for (int pt = 0; pt < 4; ++pt) {
            bf16x8 aU = *(const bf16x8*)(up + (uBaseA[pt] + k0 * 64));
#pragma unroll
            for (int p = 0; p < 4; ++p)
#pragma unroll
                for (int ot = 0; ot < 2; ++ot)
                    acc[p][pt][ot] = MFMA(aU, wb[p][ot], acc[p][pt][ot]);
        }
    }

    // relu + store: parities interleave into consecutive xo
#pragma unroll
    for (int pt = 0; pt < 4; ++pt) {
        int qy = y0 + 2 * wpi + (pt >> 1);
        int qt = pt & 1;
        int qx0 = qt * 16 + lg * 4;
        if (qx0 >= 28) continue;
#pragma unroll
        for (int ot = 0; ot < 2; ++ot) {
            int o = wo * 32 + ot * 16 + l15;
            size_t base = ((size_t)(b * NO + o) * OH + 2 * qy) * OH + 2 * qx0;
#pragma unroll
            for (int r = 0; r < 4; ++r) {
                float2 v0 = { fmaxf(acc[0][pt][ot][r], 0.f), fmaxf(acc[1][pt][ot][r], 0.f) };
                float2 v1 = { fmaxf(acc[2][pt][ot][r], 0.f), fmaxf(acc[3][pt][ot][r], 0.f) };
                *reinterpret_cast<float2*>(&out[base + 2 * r]) = v0;
                *reinterpret_cast<float2*>(&out[base + OH + 2 * r]) = v1;
            }
        }
    }
}

// ---------------------------------------------------------------------------
extern "C" void kernel_launch(void* const* d_in, const int* in_sizes, int n_in,
                              void* d_out, int out_size, void* d_ws, size_t ws_size,
                              hipStream_t stream)
{
    const float* x     = (const float*)d_in[0];
    const float* w2    = (const float*)d_in[1];
    const float* w1    = (const float*)d_in[2];
    const float* wup   = (const float*)d_in[3];
    const float* b1a   = (const float*)d_in[4];
    const float* b1b   = (const float*)d_in[5];
    const float* b2a   = (const float*)d_in[6];
    const float* b2b   = (const float*)d_in[7];
    const float* scale = (const float*)d_in[8];

    char* ws = (char*)d_ws;
    u16* xT2   = (u16*)(ws);                 // 15,728,640 B
    u16* r1T   = (u16*)(ws + 15728640);      // 15,728,640 B
    u16* xupT  = (u16*)(ws + 31457280);      //  7,340,032 B
    u16* wT2   = (u16*)(ws + 38797312);      //  1,179,648 B
    u16* wc2T  = (u16*)(ws + 39976960);      //    589,824 B
    u16* wupT  = (u16*)(ws + 40566784);      //    131,072 B
    float* rng = (float*)(ws + 40697856);    //     32,768 B
    int* sel   = (int*)(ws + 40730624);      //     16,384 B
    float* out = (float*)d_out;

    hipLaunchKernelGGL(k_pack_w,   dim3(288),  dim3(256), 0, stream, w2, wT2);
    hipLaunchKernelGGL(k_pack_wc2, dim3(144),  dim3(256), 0, stream, w1, wc2T);
    hipLaunchKernelGGL(k_pack_wup, dim3(32),   dim3(256), 0, stream, wup, wupT);
    hipLaunchKernelGGL(k_pack_x,   dim3(3840), dim3(256), 0, stream, x, b1a, xT2);
    hipLaunchKernelGGL(k_range,    dim3(NB * NC), dim3(256), 0, stream, x, rng);
    hipLaunchKernelGGL(k_select,   dim3(NB),   dim3(NC), 0, stream, rng, sel);
    hipLaunchKernelGGL(k_zero,     dim3(3840), dim3(256), 0, stream, (uint4*)r1T, 983040);
    hipLaunchKernelGGL(k_conv1_mfma, dim3(NB * 7), dim3(512), 0, stream,
                       xT2, wT2, b1b, b2a, r1T);
    hipLaunchKernelGGL(k_pack_xup, dim3(1792), dim3(256), 0, stream, x, sel, b1a, xupT);
    hipLaunchKernelGGL(k_conv2_mfma, dim3(NB * 7), dim3(512), 0, stream,
                       r1T, xupT, wc2T, wupT, scale, b2b, out);
}

// Round 7
// 143.281 us; speedup vs baseline: 12.6739x; 1.0522x over previous
//
#include <hip/hip_runtime.h>

#define NB 32      // batch
#define NC 256     // planes
#define NO 128     // inplanes (output channels)
#define HH 28
#define HW 784     // 28*28
#define OH 56

typedef unsigned short u16;
typedef __attribute__((ext_vector_type(8))) short bf16x8;
typedef __attribute__((ext_vector_type(4))) float f32x4;
typedef __attribute__((ext_vector_type(8))) unsigned short u16x8;

#define MFMA(A,B,C) __builtin_amdgcn_mfma_f32_16x16x32_bf16(A,B,C,0,0,0)

__device__ __forceinline__ u16 f2bf(float f) {
    unsigned u = __float_as_uint(f);
    unsigned r = (u + 0x7fffu + ((u >> 16) & 1u)) >> 16;
    return (u16)r;
}

// ---------------------------------------------------------------------------
// zero-fill (16B granules)
// ---------------------------------------------------------------------------
__global__ void k_zero(uint4* __restrict__ p, int n) {
    int g = blockIdx.x * 256 + threadIdx.x;
    if (g < n) p[g] = make_uint4(0, 0, 0, 0);
}

// ---------------------------------------------------------------------------
// Fused weight packs (3 former kernels, 1 launch):
//  blocks [0,288):   wT2[tap][cb][o][ci]  = w2[c][o][2-dy][2-dx]
//  blocks [288,432): wc2T[s][cb][o][ci]   = w1[c][o][tap_s], s->taps {0,2,6,8,1,7,3,5,4}
//  blocks [432,464): wupT[p][kb][o][ki]   = wup[k][o][p]
// ---------------------------------------------------------------------------
__global__ void k_pack_weights(const float* __restrict__ w2, const float* __restrict__ w1,
                               const float* __restrict__ wup,
                               u16* __restrict__ wT2, u16* __restrict__ wc2T,
                               u16* __restrict__ wupT) {
    int blk = blockIdx.x;
    if (blk < 288) {
        int g = blk * 256 + threadIdx.x;          // 9*32*256
        int o = g & 255;
        int cb = (g >> 8) & 31;
        int tap = g >> 13;
        int u = 2 - tap / 3, v = 2 - tap % 3;
        u16x8 out;
#pragma unroll
        for (int ci = 0; ci < 8; ++ci) {
            int c = cb * 8 + ci;
            out[ci] = f2bf(w2[((c * NC + o) * 3 + u) * 3 + v]);
        }
        *(u16x8*)(wT2 + (size_t)g * 8) = out;
    } else if (blk < 432) {
        const int taps[9] = {0, 2, 6, 8, 1, 7, 3, 5, 4};
        int g = (blk - 288) * 256 + threadIdx.x;  // 9*32*128
        int o = g & 127;
        int cb = (g >> 7) & 31;
        int s = g >> 12;
        int tap = taps[s];
        u16x8 out;
#pragma unroll
        for (int ci = 0; ci < 8; ++ci) {
            int c = cb * 8 + ci;
            out[ci] = f2bf(w1[(c * NO + o) * 9 + tap]);
        }
        *(u16x8*)(wc2T + (size_t)g * 8) = out;
    } else {
        int g = (blk - 432) * 256 + threadIdx.x;  // 4*16*128
        int o = g & 127;
        int kb = (g >> 7) & 15;
        int p = g >> 11;
        u16x8 out;
#pragma unroll
        for (int ki = 0; ki < 8; ++ki) {
            int k = kb * 8 + ki;
            out[ki] = f2bf(wup[(k * NO + o) * 4 + p]);
        }
        *(u16x8*)(wupT + (size_t)g * 8) = out;
    }
}

// ---------------------------------------------------------------------------
// Pack x: xT2[b][ry 0..29][cb][cx 0..31][ci], value = x[b][c][ry-1][cx-1]+b1a or 0
// ---------------------------------------------------------------------------
__global__ void k_pack_x(const float* __restrict__ x, const float* __restrict__ pb1a,
                         u16* __restrict__ xT2) {
    int g = blockIdx.x * 256 + threadIdx.x;          // 32*30*32*32 = 983040
    float b1a = pb1a[0];
    int cx = g & 31;
    int cb = (g >> 5) & 31;
    int bry = g >> 10;
    int b = bry / 30;
    int ry = bry - b * 30;
    int y = ry - 1, xx = cx - 1;
    bool valid = (y >= 0 && y < HH && xx >= 0 && xx < HH);
    const float* xb = x + (size_t)b * NC * HW + (valid ? y * 28 + xx : 0);
    u16x8 out;
#pragma unroll
    for (int ci = 0; ci < 8; ++ci) {
        float f = valid ? xb[(cb * 8 + ci) * HW] + b1a : 0.f;
        out[ci] = f2bf(f);
    }
    *(u16x8*)(xT2 + (size_t)g * 8) = out;
}

// ---------------------------------------------------------------------------
// Gather-pack selected channels: xupT[b][qy][kb][cx][ki] = x[b][sel[k]][qy][cx]+b1a
// ---------------------------------------------------------------------------
__global__ void k_pack_xup(const float* __restrict__ x, const int* __restrict__ sel,
                           const float* __restrict__ pb1a, u16* __restrict__ xupT) {
    int g = blockIdx.x * 256 + threadIdx.x;          // 32*28*16*32 = 458752
    float b1a = pb1a[0];
    int cx = g & 31;
    int kb = (g >> 5) & 15;
    int qyb = g >> 9;
    int b = qyb / 28;
    int qy = qyb - b * 28;
    bool valid = cx < 28;
    const int* selb = sel + b * NO;
    const float* xb = x + (size_t)b * NC * HW + qy * 28 + (valid ? cx : 0);
    u16x8 out;
#pragma unroll
    for (int ki = 0; ki < 8; ++ki) {
        int ch = selb[kb * 8 + ki];
        float f = valid ? xb[ch * HW] + b1a : 0.f;
        out[ki] = f2bf(f);
    }
    *(u16x8*)(xupT + (size_t)g * 8) = out;
}

// ---------------------------------------------------------------------------
// K1: per-(b,c) range
// ---------------------------------------------------------------------------
__global__ void k_range(const float* __restrict__ x, float* __restrict__ rng) {
    int bc = blockIdx.x;
    int t = threadIdx.x;
    const float* p = x + (size_t)bc * HW;
    float mx = -1e30f, mn = 1e30f;
    for (int i = t; i < HW; i += 256) {
        float v = p[i];
        mx = fmaxf(mx, v);
        mn = fminf(mn, v);
    }
    __shared__ float smx[256], smn[256];
    smx[t] = mx; smn[t] = mn;
    __syncthreads();
    for (int s = 128; s > 0; s >>= 1) {
        if (t < s) {
            smx[t] = fmaxf(smx[t], smx[t + s]);
            smn[t] = fminf(smn[t], smn[t + s]);
        }
        __syncthreads();
    }
    if (t == 0) rng[bc] = smx[0] - smn[0];
}

// ---------------------------------------------------------------------------
// K2: stable argsort rank; keep top half ascending
// ---------------------------------------------------------------------------
__global__ void k_select(const float* __restrict__ rng, int* __restrict__ sel) {
    int b = blockIdx.x;
    int c = threadIdx.x;
    __shared__ float s[NC];
    s[c] = rng[b * NC + c];
    __syncthreads();
    float v = s[c];
    int rank = 0;
    for (int j = 0; j < NC; ++j) {
        float u = s[j];
        rank += (u < v) || (u == v && j < c);
    }
    if (rank >= NC / 2) sel[b * (NC / 2) + (rank - NC / 2)] = c;
}

// ---------------------------------------------------------------------------
// conv1 via MFMA -> r1T[b][ry][cb][cx][ci] (padded layout, pre-zeroed ring)
// Re-tiled for occupancy: block = 4 rows x 32 cx x 128 o (o split across 2
// blocks), 8 waves = 2M x 4N, wave = 4Mt x 2Nt (acc 32). Grid 448, 3584 waves.
// ---------------------------------------------------------------------------
__global__ __launch_bounds__(512, 4) void k_conv1_mfma(
    const u16* __restrict__ xT2, const u16* __restrict__ wT2,
    const float* __restrict__ pb1b, const float* __restrict__ pb2a,
    u16* __restrict__ r1T)
{
    int tid = threadIdx.x;
    int wave = tid >> 6, lane = tid & 63;
    int wpi = wave >> 2;              // M-group 0..1
    int wo = wave & 3;                // N-group 0..3 (32 o each)
    int l15 = lane & 15, lg = lane >> 4;

    int idx = blockIdx.x;             // 448 = 32b * 7rg * 2og
    int b = idx / 14;
    int rem = idx - b * 14;
    int rg = rem >> 1;
    int og = rem & 1;
    int y0 = rg * 4;

    float b1b = pb1b[0], b2a = pb2a[0];

    int aOff[4], bOff[2];
#pragma unroll
    for (int pt = 0; pt < 4; ++pt) {
        int ry = y0 + 2 * wpi + (pt >> 1);
        int cx = (pt & 1) * 16 + l15;
        aOff[pt] = (((b * 30 + ry) * 32 + lg) * 32 + cx) * 16;
    }
#pragma unroll
    for (int ot = 0; ot < 2; ++ot)
        bOff[ot] = (lg * 256 + (og * 128 + wo * 32 + ot * 16 + l15)) * 16;

    f32x4 acc[4][2] = {};
    const char* xp = (const char*)xT2;
    const char* wq = (const char*)wT2;

    for (int c0 = 0; c0 < 256; c0 += 32) {
#pragma unroll
        for (int tap = 0; tap < 9; ++tap) {
            const int dy = tap / 3, dx = tap % 3;
            int koffA = c0 * 64 + dy * 16384 + dx * 16;
            int koffB = tap * 131072 + c0 * 512;
            bf16x8 a[4], w[2];
#pragma unroll
            for (int pt = 0; pt < 4; ++pt)
                a[pt] = *(const bf16x8*)(xp + (aOff[pt] + koffA));
#pragma unroll
            for (int ot = 0; ot < 2; ++ot)
                w[ot] = *(const bf16x8*)(wq + (bOff[ot] + koffB));
#pragma unroll
            for (int pt = 0; pt < 4; ++pt)
#pragma unroll
                for (int ot = 0; ot < 2; ++ot)
                    acc[pt][ot] = MFMA(a[pt], w[ot], acc[pt][ot]);
        }
    }

    // epilogue: relu(acc+b1b)+b2a -> r1T[b][y+1][o/8][x+1][o%8]
#pragma unroll
    for (int pt = 0; pt < 4; ++pt) {
        int y = y0 + 2 * wpi + (pt >> 1);
        int x0 = (pt & 1) * 16 + lg * 4;
        if (x0 >= 28) continue;
#pragma unroll
        for (int ot = 0; ot < 2; ++ot) {
            int o = og * 128 + wo * 32 + ot * 16 + l15;
            size_t base = ((((size_t)b * 30 + y + 1) * 32 + (o >> 3)) * 32 + (x0 + 1)) * 8 + (o & 7);
#pragma unroll
            for (int r = 0; r < 4; ++r) {
                float f = fmaxf(acc[pt][ot][r] + b1b, 0.f) + b2a;
                r1T[base + (size_t)r * 8] = f2bf(f);
            }
        }
    }
}

// ---------------------------------------------------------------------------
// conv2 + upsample via MFMA (unchanged control this round).
// ---------------------------------------------------------------------------
__global__ __launch_bounds__(512, 2) void k_conv2_mfma(
    const u16* __restrict__ r1T, const u16* __restrict__ xupT,
    const u16* __restrict__ wc2T, const u16* __restrict__ wupT,
    const float* __restrict__ pscale, const float* __restrict__ pb2b,
    float* __restrict__ out)
{
    int tid = threadIdx.x;
    int wave = tid >> 6, lane = tid & 63;
    int wpi = wave >> 2;
    int wo = wave & 3;
    int l15 = lane & 15, lg = lane >> 4;

    int b = blockIdx.x / 7;
    int rg = blockIdx.x - b * 7;
    int y0 = rg * 4;

    float scale = pscale[0], b2b = pb2b[0];

    f32x4 acc[4][4][2] = {};   // [parity][pixel-tile][o-tile]

    const char* rp = (const char*)r1T;
    const char* wp = (const char*)wc2T;

    int aBase[4];
#pragma unroll
    for (int pt = 0; pt < 4; ++pt) {
        int qy = y0 + 2 * wpi + (pt >> 1);
        int qt = pt & 1;
        aBase[pt] = (((b * 30 + qy + 1) * 32 + lg) * 32 + (qt * 16 + l15 + 1)) * 16;
    }
    int bBase = (lg * 128 + wo * 32 + l15) * 16;

    for (int c0 = 0; c0 < 256; c0 += 32) {
        bf16x8 w[9][2];
#pragma unroll
        for (int s = 0; s < 9; ++s)
#pragma unroll
            for (int ot = 0; ot < 2; ++ot)
                w[s][ot] = *(const bf16x8*)(wp + (bBase + s * 65536 + c0 * 256 + ot * 256));
#pragma unroll
        for (int pt = 0; pt < 4; ++pt) {
            const char* ap = rp + (aBase[pt] + c0 * 64);
            bf16x8 aD = *(const bf16x8*)(ap);
            bf16x8 aC = *(const bf16x8*)(ap - 16);
            bf16x8 aB = *(const bf16x8*)(ap - 16384);
            bf16x8 aA = *(const bf16x8*)(ap - 16400);
#pragma unroll
            for (int ot = 0; ot < 2; ++ot) {
                acc[0][pt][ot] = MFMA(aD, w[0][ot], acc[0][pt][ot]);
                acc[0][pt][ot] = MFMA(aC, w[1][ot], acc[0][pt][ot]);
                acc[0][pt][ot] = MFMA(aB, w[2][ot], acc[0][pt][ot]);
                acc[0][pt][ot] = MFMA(aA, w[3][ot], acc[0][pt][ot]);
                acc[1][pt][ot] = MFMA(aD, w[4][ot], acc[1][pt][ot]);
                acc[1][pt][ot] = MFMA(aB, w[5][ot], acc[1][pt][ot]);
                acc[2][pt][ot] = MFMA(aD, w[6][ot], acc[2][pt][ot]);
                acc[2][pt][ot] = MFMA(aC, w[7][ot], acc[2][pt][ot]);
                acc[3][pt][ot] = MFMA(aD, w[8][ot], acc[3][pt][ot]);
            }
        }
    }

    // mid-transform: pad-zero / scale+b2b (before upsample accumulation)
#pragma unroll
    for (int pt = 0; pt < 4; ++pt) {
        int qy = y0 + 2 * wpi + (pt >> 1);
        int qt = pt & 1;
        int qx0 = qt * 16 + lg * 4;
        bool zr = (qy == 0);
#pragma unroll
        for (int ot = 0; ot < 2; ++ot)
#pragma unroll
            for (int r = 0; r < 4; ++r) {
                bool zc = (qx0 + r == 0);
                float a0 = acc[0][pt][ot][r], a1 = acc[1][pt][ot][r];
                float a2 = acc[2][pt][ot][r], a3 = acc[3][pt][ot][r];
                acc[0][pt][ot][r] = (zr || zc) ? 0.f : fmaf(a0, scale, b2b);
                acc[1][pt][ot][r] = zr ? 0.f : fmaf(a1, scale, b2b);
                acc[2][pt][ot][r] = zc ? 0.f : fmaf(a2, scale, b2b);
                acc[3][pt][ot][r] = fmaf(a3, scale, b2b);
            }
    }

    // upsample accumulation
    const char* up = (const char*)xupT;
    const char* wu = (const char*)wupT;
    int uBaseA[4];
#pragma unroll
    for (int pt = 0; pt < 4; ++pt) {
        int qy = y0 + 2 * wpi + (pt >> 1);
        int qt = pt & 1;
        uBaseA[pt] = (((b * 28 + qy) * 16 + lg) * 32 + (qt * 16 + l15)) * 16;
    }
    for (int k0 = 0; k0 < 128; k0 += 32) {
        bf16x8 wb[4][2];
#pragma unroll
        for (int p = 0; p < 4; ++p)
#pragma unroll
            for (int ot = 0; ot < 2; ++ot)
                wb[p][ot] = *(const bf16x8*)(wu + (bBase + p * 32768 + k0 * 256 + ot * 256));
#pragma unroll
        for (int pt = 0; pt < 4; ++pt) {
            bf16x8 aU = *(const bf16x8*)(up + (uBaseA[pt] + k0 * 64));
#pragma unroll
            for (int p = 0; p < 4; ++p)
#pragma unroll
                for (int ot = 0; ot < 2; ++ot)
                    acc[p][pt][ot] = MFMA(aU, wb[p][ot], acc[p][pt][ot]);
        }
    }

    // relu + store
#pragma unroll
    for (int pt = 0; pt < 4; ++pt) {
        int qy = y0 + 2 * wpi + (pt >> 1);
        int qt = pt & 1;
        int qx0 = qt * 16 + lg * 4;
        if (qx0 >= 28) continue;
#pragma unroll
        for (int ot = 0; ot < 2; ++ot) {
            int o = wo * 32 + ot * 16 + l15;
            size_t base = ((size_t)(b * NO + o) * OH + 2 * qy) * OH + 2 * qx0;
#pragma unroll
            for (int r = 0; r < 4; ++r) {
                float2 v0 = { fmaxf(acc[0][pt][ot][r], 0.f), fmaxf(acc[1][pt][ot][r], 0.f) };
                float2 v1 = { fmaxf(acc[2][pt][ot][r], 0.f), fmaxf(acc[3][pt][ot][r], 0.f) };
                *reinterpret_cast<float2*>(&out[base + 2 * r]) = v0;
                *reinterpret_cast<float2*>(&out[base + OH + 2 * r]) = v1;
            }
        }
    }
}

// ---------------------------------------------------------------------------
extern "C" void kernel_launch(void* const* d_in, const int* in_sizes, int n_in,
                              void* d_out, int out_size, void* d_ws, size_t ws_size,
                              hipStream_t stream)
{
    const float* x     = (const float*)d_in[0];
    const float* w2    = (const float*)d_in[1];
    const float* w1    = (const float*)d_in[2];
    const float* wup   = (const float*)d_in[3];
    const float* b1a   = (const float*)d_in[4];
    const float* b1b   = (const float*)d_in[5];
    const float* b2a   = (const float*)d_in[6];
    const float* b2b   = (const float*)d_in[7];
    const float* scale = (const float*)d_in[8];

    char* ws = (char*)d_ws;
    u16* xT2   = (u16*)(ws);                 // 15,728,640 B
    u16* r1T   = (u16*)(ws + 15728640);      // 15,728,640 B
    u16* xupT  = (u16*)(ws + 31457280);      //  7,340,032 B
    u16* wT2   = (u16*)(ws + 38797312);      //  1,179,648 B
    u16* wc2T  = (u16*)(ws + 39976960);      //    589,824 B
    u16* wupT  = (u16*)(ws + 40566784);      //    131,072 B
    float* rng = (float*)(ws + 40697856);    //     32,768 B
    int* sel   = (int*)(ws + 40730624);      //     16,384 B
    float* out = (float*)d_out;

    hipLaunchKernelGGL(k_pack_weights, dim3(464), dim3(256), 0, stream,
                       w2, w1, wup, wT2, wc2T, wupT);
    hipLaunchKernelGGL(k_pack_x,   dim3(3840), dim3(256), 0, stream, x, b1a, xT2);
    hipLaunchKernelGGL(k_range,    dim3(NB * NC), dim3(256), 0, stream, x, rng);
    hipLaunchKernelGGL(k_select,   dim3(NB),   dim3(NC), 0, stream, rng, sel);
    hipLaunchKernelGGL(k_zero,     dim3(3840), dim3(256), 0, stream, (uint4*)r1T, 983040);
    hipLaunchKernelGGL(k_conv1_mfma, dim3(448), dim3(512), 0, stream,
                       xT2, wT2, b1b, b2a, r1T);
    hipLaunchKernelGGL(k_pack_xup, dim3(1792), dim3(256), 0, stream, x, sel, b1a, xupT);
    hipLaunchKernelGGL(k_conv2_mfma, dim3(NB * 7), dim3(512), 0, stream,
                       r1T, xupT, wc2T, wupT, scale, b2b, out);
}

// Round 8
// 133.344 us; speedup vs baseline: 13.6184x; 1.0745x over previous
//
#include <hip/hip_runtime.h>

#define NB 32      // batch
#define NC 256     // planes
#define NO 128     // inplanes (output channels)
#define HH 28
#define HW 784     // 28*28
#define OH 56

typedef unsigned short u16;
typedef __attribute__((ext_vector_type(8))) short bf16x8;
typedef __attribute__((ext_vector_type(4))) float f32x4;
typedef __attribute__((ext_vector_type(8))) unsigned short u16x8;

#define MFMA(A,B,C) __builtin_amdgcn_mfma_f32_16x16x32_bf16(A,B,C,0,0,0)

__device__ __forceinline__ u16 f2bf(float f) {
    unsigned u = __float_as_uint(f);
    unsigned r = (u + 0x7fffu + ((u >> 16) & 1u)) >> 16;
    return (u16)r;
}

// ---------------------------------------------------------------------------
// zero-fill (16B granules)
// ---------------------------------------------------------------------------
__global__ void k_zero(uint4* __restrict__ p, int n) {
    int g = blockIdx.x * 256 + threadIdx.x;
    if (g < n) p[g] = make_uint4(0, 0, 0, 0);
}

// ---------------------------------------------------------------------------
// Fused weight packs:
//  blocks [0,288):   wT2[tap][cb][o][ci]  = w2[c][o][2-dy][2-dx]
//  blocks [288,432): wc2T[s][cb][o][ci]   = w1[c][o][tap_s], s->taps {0,2,6,8,1,7,3,5,4}
//  blocks [432,464): wupT[p][kb][o][ki]   = wup[k][o][p]
// ---------------------------------------------------------------------------
__global__ void k_pack_weights(const float* __restrict__ w2, const float* __restrict__ w1,
                               const float* __restrict__ wup,
                               u16* __restrict__ wT2, u16* __restrict__ wc2T,
                               u16* __restrict__ wupT) {
    int blk = blockIdx.x;
    if (blk < 288) {
        int g = blk * 256 + threadIdx.x;          // 9*32*256
        int o = g & 255;
        int cb = (g >> 8) & 31;
        int tap = g >> 13;
        int u = 2 - tap / 3, v = 2 - tap % 3;
        u16x8 out;
#pragma unroll
        for (int ci = 0; ci < 8; ++ci) {
            int c = cb * 8 + ci;
            out[ci] = f2bf(w2[((c * NC + o) * 3 + u) * 3 + v]);
        }
        *(u16x8*)(wT2 + (size_t)g * 8) = out;
    } else if (blk < 432) {
        const int taps[9] = {0, 2, 6, 8, 1, 7, 3, 5, 4};
        int g = (blk - 288) * 256 + threadIdx.x;  // 9*32*128
        int o = g & 127;
        int cb = (g >> 7) & 31;
        int s = g >> 12;
        int tap = taps[s];
        u16x8 out;
#pragma unroll
        for (int ci = 0; ci < 8; ++ci) {
            int c = cb * 8 + ci;
            out[ci] = f2bf(w1[(c * NO + o) * 9 + tap]);
        }
        *(u16x8*)(wc2T + (size_t)g * 8) = out;
    } else {
        int g = (blk - 432) * 256 + threadIdx.x;  // 4*16*128
        int o = g & 127;
        int kb = (g >> 7) & 15;
        int p = g >> 11;
        u16x8 out;
#pragma unroll
        for (int ki = 0; ki < 8; ++ki) {
            int k = kb * 8 + ki;
            out[ki] = f2bf(wup[(k * NO + o) * 4 + p]);
        }
        *(u16x8*)(wupT + (size_t)g * 8) = out;
    }
}

// ---------------------------------------------------------------------------
// Pack x: xT2[b][ry 0..29][cb][cx 0..31][ci], value = x[b][c][ry-1][cx-1]+b1a or 0
// ---------------------------------------------------------------------------
__global__ void k_pack_x(const float* __restrict__ x, const float* __restrict__ pb1a,
                         u16* __restrict__ xT2) {
    int g = blockIdx.x * 256 + threadIdx.x;          // 32*30*32*32 = 983040
    float b1a = pb1a[0];
    int cx = g & 31;
    int cb = (g >> 5) & 31;
    int bry = g >> 10;
    int b = bry / 30;
    int ry = bry - b * 30;
    int y = ry - 1, xx = cx - 1;
    bool valid = (y >= 0 && y < HH && xx >= 0 && xx < HH);
    const float* xb = x + (size_t)b * NC * HW + (valid ? y * 28 + xx : 0);
    u16x8 out;
#pragma unroll
    for (int ci = 0; ci < 8; ++ci) {
        float f = valid ? xb[(cb * 8 + ci) * HW] + b1a : 0.f;
        out[ci] = f2bf(f);
    }
    *(u16x8*)(xT2 + (size_t)g * 8) = out;
}

// ---------------------------------------------------------------------------
// Gather-pack selected channels: xupT[b][qy][kb][cx][ki] = x[b][sel[k]][qy][cx]+b1a
// ---------------------------------------------------------------------------
__global__ void k_pack_xup(const float* __restrict__ x, const int* __restrict__ sel,
                           const float* __restrict__ pb1a, u16* __restrict__ xupT) {
    int g = blockIdx.x * 256 + threadIdx.x;          // 32*28*16*32 = 458752
    float b1a = pb1a[0];
    int cx = g & 31;
    int kb = (g >> 5) & 15;
    int qyb = g >> 9;
    int b = qyb / 28;
    int qy = qyb - b * 28;
    bool valid = cx < 28;
    const int* selb = sel + b * NO;
    const float* xb = x + (size_t)b * NC * HW + qy * 28 + (valid ? cx : 0);
    u16x8 out;
#pragma unroll
    for (int ki = 0; ki < 8; ++ki) {
        int ch = selb[kb * 8 + ki];
        float f = valid ? xb[ch * HW] + b1a : 0.f;
        out[ki] = f2bf(f);
    }
    *(u16x8*)(xupT + (size_t)g * 8) = out;
}

// ---------------------------------------------------------------------------
// K1: per-(b,c) range
// ---------------------------------------------------------------------------
__global__ void k_range(const float* __restrict__ x, float* __restrict__ rng) {
    int bc = blockIdx.x;
    int t = threadIdx.x;
    const float* p = x + (size_t)bc * HW;
    float mx = -1e30f, mn = 1e30f;
    for (int i = t; i < HW; i += 256) {
        float v = p[i];
        mx = fmaxf(mx, v);
        mn = fminf(mn, v);
    }
    __shared__ float smx[256], smn[256];
    smx[t] = mx; smn[t] = mn;
    __syncthreads();
    for (int s = 128; s > 0; s >>= 1) {
        if (t < s) {
            smx[t] = fmaxf(smx[t], smx[t + s]);
            smn[t] = fminf(smn[t], smn[t + s]);
        }
        __syncthreads();
    }
    if (t == 0) rng[bc] = smx[0] - smn[0];
}

// ---------------------------------------------------------------------------
// K2: stable argsort rank; keep top half ascending
// ---------------------------------------------------------------------------
__global__ void k_select(const float* __restrict__ rng, int* __restrict__ sel) {
    int b = blockIdx.x;
    int c = threadIdx.x;
    __shared__ float s[NC];
    s[c] = rng[b * NC + c];
    __syncthreads();
    float v = s[c];
    int rank = 0;
    for (int j = 0; j < NC; ++j) {
        float u = s[j];
        rank += (u < v) || (u == v && j < c);
    }
    if (rank >= NC / 2) sel[b * (NC / 2) + (rank - NC / 2)] = c;
}

// ---------------------------------------------------------------------------
// conv1 via MFMA, A-slab in LDS.
// Block: batch b, 4 output rows, 32 cx, ALL 256 o. Grid 224.
// LDS: whole A-slab = 6 padded rows x 32 cb x 32 cx x 8 ci bf16 = 96 KB,
// staged once (linear copy of contiguous xT2 region), one barrier.
// 8 waves = 2(wpi: row pairs) x 4(wo: 64-o groups); wave = 4pt x 4ot,
// acc 4x4xf32x4 = 64 VGPR. A-frags from LDS (4 per tap, shared over 4 ot);
// B-frags direct from global (wT2 1.15MB, L2-resident; reused over 4 pt).
// ---------------------------------------------------------------------------
__global__ __launch_bounds__(512, 2) void k_conv1_mfma(
    const u16* __restrict__ xT2, const u16* __restrict__ wT2,
    const float* __restrict__ pb1b, const float* __restrict__ pb2a,
    u16* __restrict__ r1T)
{
    __shared__ u16 sA[6 * 32 * 32 * 8];   // 98304 B
    int tid = threadIdx.x;
    int wave = tid >> 6, lane = tid & 63;
    int wpi = wave >> 2;              // 0..1: rows {2wpi, 2wpi+1}
    int wo = wave & 3;                // 0..3: o-group of 64
    int l15 = lane & 15, lg = lane >> 4;

    int b = blockIdx.x / 7;
    int rg = blockIdx.x - b * 7;
    int y0 = rg * 4;

    float b1b = pb1b[0], b2a = pb2a[0];

    // stage whole A-slab: rows y0..y0+5, all cb/cx/ci -> 6144 uint4 slots
    {
        const uint4* src = (const uint4*)(xT2 + (size_t)(b * 30 + y0) * 8192);
        uint4* dst = (uint4*)sA;
#pragma unroll
        for (int i = 0; i < 12; ++i)
            dst[tid + i * 512] = src[tid + i * 512];
    }
    __syncthreads();

    int bOff[4];
#pragma unroll
    for (int ot = 0; ot < 4; ++ot)
        bOff[ot] = (lg * 256 + (wo * 64 + ot * 16 + l15)) * 16;

    f32x4 acc[4][4] = {};   // [pt = m*2+h][ot]
    const char* wq = (const char*)wT2;
    const char* ap0 = (const char*)sA;

    for (int c0 = 0; c0 < 256; c0 += 32) {
        int cbByte = c0 * 64;             // (c0/8)*512
#pragma unroll
        for (int dy = 0; dy < 3; ++dy) {
#pragma unroll
            for (int dx = 0; dx < 3; ++dx) {
                int tap = dy * 3 + dx;
                bf16x8 w[4];
#pragma unroll
                for (int ot = 0; ot < 4; ++ot)
                    w[ot] = *(const bf16x8*)(wq + (bOff[ot] + tap * 131072 + c0 * 512));
                bf16x8 a[2][2];
#pragma unroll
                for (int m = 0; m < 2; ++m)
#pragma unroll
                    for (int h = 0; h < 2; ++h)
                        a[m][h] = *(const bf16x8*)(ap0 +
                            (2 * wpi + m + dy) * 16384 + cbByte + lg * 512 +
                            (h * 16 + l15 + dx) * 16);
#pragma unroll
                for (int m = 0; m < 2; ++m)
#pragma unroll
                    for (int h = 0; h < 2; ++h)
#pragma unroll
                        for (int ot = 0; ot < 4; ++ot)
                            acc[m * 2 + h][ot] = MFMA(a[m][h], w[ot], acc[m * 2 + h][ot]);
            }
        }
    }

    // epilogue: relu(acc+b1b)+b2a -> r1T[b][y+1][o/8][x+1][o%8]
#pragma unroll
    for (int m = 0; m < 2; ++m)
#pragma unroll
        for (int h = 0; h < 2; ++h) {
            int y = y0 + 2 * wpi + m;
            int x0 = h * 16 + lg * 4;
            if (x0 >= 28) continue;
#pragma unroll
            for (int ot = 0; ot < 4; ++ot) {
                int o = wo * 64 + ot * 16 + l15;
                size_t base = ((((size_t)b * 30 + y + 1) * 32 + (o >> 3)) * 32 + (x0 + 1)) * 8 + (o & 7);
#pragma unroll
                for (int r = 0; r < 4; ++r) {
                    float f = fmaxf(acc[m * 2 + h][ot][r] + b1b, 0.f) + b2a;
                    r1T[base + (size_t)r * 8] = f2bf(f);
                }
            }
        }
}

// ---------------------------------------------------------------------------
// conv2 + upsample via MFMA (unchanged control this round).
// ---------------------------------------------------------------------------
__global__ __launch_bounds__(512, 2) void k_conv2_mfma(
    const u16* __restrict__ r1T, const u16* __restrict__ xupT,
    const u16* __restrict__ wc2T, const u16* __restrict__ wupT,
    const float* __restrict__ pscale, const float* __restrict__ pb2b,
    float* __restrict__ out)
{
    int tid = threadIdx.x;
    int wave = tid >> 6, lane = tid & 63;
    int wpi = wave >> 2;
    int wo = wave & 3;
    int l15 = lane & 15, lg = lane >> 4;

    int b = blockIdx.x / 7;
    int rg = blockIdx.x - b * 7;
    int y0 = rg * 4;

    float scale = pscale[0], b2b = pb2b[0];

    f32x4 acc[4][4][2] = {};   // [parity][pixel-tile][o-tile]

    const char* rp = (const char*)r1T;
    const char* wp = (const char*)wc2T;

    int aBase[4];
#pragma unroll
    for (int pt = 0; pt < 4; ++pt) {
        int qy = y0 + 2 * wpi + (pt >> 1);
        int qt = pt & 1;
        aBase[pt] = (((b * 30 + qy + 1) * 32 + lg) * 32 + (qt * 16 + l15 + 1)) * 16;
    }
    int bBase = (lg * 128 + wo * 32 + l15) * 16;

    for (int c0 = 0; c0 < 256; c0 += 32) {
        bf16x8 w[9][2];
#pragma unroll
        for (int s = 0; s < 9; ++s)
#pragma unroll
            for (int ot = 0; ot < 2; ++ot)
                w[s][ot] = *(const bf16x8*)(wp + (bBase + s * 65536 + c0 * 256 + ot * 256));
#pragma unroll
        for (int pt = 0; pt < 4; ++pt) {
            const char* ap = rp + (aBase[pt] + c0 * 64);
            bf16x8 aD = *(const bf16x8*)(ap);
            bf16x8 aC = *(const bf16x8*)(ap - 16);
            bf16x8 aB = *(const bf16x8*)(ap - 16384);
            bf16x8 aA = *(const bf16x8*)(ap - 16400);
#pragma unroll
            for (int ot = 0; ot < 2; ++ot) {
                acc[0][pt][ot] = MFMA(aD, w[0][ot], acc[0][pt][ot]);
                acc[0][pt][ot] = MFMA(aC, w[1][ot], acc[0][pt][ot]);
                acc[0][pt][ot] = MFMA(aB, w[2][ot], acc[0][pt][ot]);
                acc[0][pt][ot] = MFMA(aA, w[3][ot], acc[0][pt][ot]);
                acc[1][pt][ot] = MFMA(aD, w[4][ot], acc[1][pt][ot]);
                acc[1][pt][ot] = MFMA(aB, w[5][ot], acc[1][pt][ot]);
                acc[2][pt][ot] = MFMA(aD, w[6][ot], acc[2][pt][ot]);
                acc[2][pt][ot] = MFMA(aC, w[7][ot], acc[2][pt][ot]);
                acc[3][pt][ot] = MFMA(aD, w[8][ot], acc[3][pt][ot]);
            }
        }
    }

    // mid-transform: pad-zero / scale+b2b (before upsample accumulation)
#pragma unroll
    for (int pt = 0; pt < 4; ++pt) {
        int qy = y0 + 2 * wpi + (pt >> 1);
        int qt = pt & 1;
        int qx0 = qt * 16 + lg * 4;
        bool zr = (qy == 0);
#pragma unroll
        for (int ot = 0; ot < 2; ++ot)
#pragma unroll
            for (int r = 0; r < 4; ++r) {
                bool zc = (qx0 + r == 0);
                float a0 = acc[0][pt][ot][r], a1 = acc[1][pt][ot][r];
                float a2 = acc[2][pt][ot][r], a3 = acc[3][pt][ot][r];
                acc[0][pt][ot][r] = (zr || zc) ? 0.f : fmaf(a0, scale, b2b);
                acc[1][pt][ot][r] = zr ? 0.f : fmaf(a1, scale, b2b);
                acc[2][pt][ot][r] = zc ? 0.f : fmaf(a2, scale, b2b);
                acc[3][pt][ot][r] = fmaf(a3, scale, b2b);
            }
    }

    // upsample accumulation
    const char* up = (const char*)xupT;
    const char* wu = (const char*)wupT;
    int uBaseA[4];
#pragma unroll
    for (int pt = 0; pt < 4; ++pt) {
        int qy = y0 + 2 * wpi + (pt >> 1);
        int qt = pt & 1;
        uBaseA[pt] = (((b * 28 + qy) * 16 + lg) * 32 + (qt * 16 + l15)) * 16;
    }
    for (int k0 = 0; k0 < 128; k0 += 32) {
        bf16x8 wb[4][2];
#pragma unroll
        for (int p = 0; p < 4; ++p)
#pragma unroll
            for (int ot = 0; ot < 2; ++ot)
                wb[p][ot] = *(const bf16x8*)(wu + (bBase + p * 32768 + k0 * 256 + ot * 256));
#pragma unroll
        for (int pt = 0; pt < 4; ++pt) {
            bf16x8 aU = *(const bf16x8*)(up + (uBaseA[pt] + k0 * 64));
#pragma unroll
            for (int p = 0; p < 4; ++p)
#pragma unroll
                for (int ot = 0; ot < 2; ++ot)
                    acc[p][pt][ot] = MFMA(aU, wb[p][ot], acc[p][pt][ot]);
        }
    }

    // relu + store
#pragma unroll
    for (int pt = 0; pt < 4; ++pt) {
        int qy = y0 + 2 * wpi + (pt >> 1);
        int qt = pt & 1;
        int qx0 = qt * 16 + lg * 4;
        if (qx0 >= 28) continue;
#pragma unroll
        for (int ot = 0; ot < 2; ++ot) {
            int o = wo * 32 + ot * 16 + l15;
            size_t base = ((size_t)(b * NO + o) * OH + 2 * qy) * OH + 2 * qx0;
#pragma unroll
            for (int r = 0; r < 4; ++r) {
                float2 v0 = { fmaxf(acc[0][pt][ot][r], 0.f), fmaxf(acc[1][pt][ot][r], 0.f) };
                float2 v1 = { fmaxf(acc[2][pt][ot][r], 0.f), fmaxf(acc[3][pt][ot][r], 0.f) };
                *reinterpret_cast<float2*>(&out[base + 2 * r]) = v0;
                *reinterpret_cast<float2*>(&out[base + OH + 2 * r]) = v1;
            }
        }
    }
}

// ---------------------------------------------------------------------------
extern "C" void kernel_launch(void* const* d_in, const int* in_sizes, int n_in,
                              void* d_out, int out_size, void* d_ws, size_t ws_size,
                              hipStream_t stream)
{
    const float* x     = (const float*)d_in[0];
    const float* w2    = (const float*)d_in[1];
    const float* w1    = (const float*)d_in[2];
    const float* wup   = (const float*)d_in[3];
    const float* b1a   = (const float*)d_in[4];
    const float* b1b   = (const float*)d_in[5];
    const float* b2a   = (const float*)d_in[6];
    const float* b2b   = (const float*)d_in[7];
    const float* scale = (const float*)d_in[8];

    char* ws = (char*)d_ws;
    u16* xT2   = (u16*)(ws);                 // 15,728,640 B
    u16* r1T   = (u16*)(ws + 15728640);      // 15,728,640 B
    u16* xupT  = (u16*)(ws + 31457280);      //  7,340,032 B
    u16* wT2   = (u16*)(ws + 38797312);      //  1,179,648 B
    u16* wc2T  = (u16*)(ws + 39976960);      //    589,824 B
    u16* wupT  = (u16*)(ws + 40566784);      //    131,072 B
    float* rng = (float*)(ws + 40697856);    //     32,768 B
    int* sel   = (int*)(ws + 40730624);      //     16,384 B
    float* out = (float*)d_out;

    hipLaunchKernelGGL(k_pack_weights, dim3(464), dim3(256), 0, stream,
                       w2, w1, wup, wT2, wc2T, wupT);
    hipLaunchKernelGGL(k_pack_x,   dim3(3840), dim3(256), 0, stream, x, b1a, xT2);
    hipLaunchKernelGGL(k_range,    dim3(NB * NC), dim3(256), 0, stream, x, rng);
    hipLaunchKernelGGL(k_select,   dim3(NB),   dim3(NC), 0, stream, rng, sel);
    hipLaunchKernelGGL(k_zero,     dim3(3840), dim3(256), 0, stream, (uint4*)r1T, 983040);
    hipLaunchKernelGGL(k_conv1_mfma, dim3(224), dim3(512), 0, stream,
                       xT2, wT2, b1b, b2a, r1T);
    hipLaunchKernelGGL(k_pack_xup, dim3(1792), dim3(256), 0, stream, x, sel, b1a, xupT);
    hipLaunchKernelGGL(k_conv2_mfma, dim3(NB * 7), dim3(512), 0, stream,
                       r1T, xupT, wc2T, wupT, scale, b2b, out);
}